// Round 7
// baseline (153.280 us; speedup 1.0000x reference)
//
#include <hip/hip_runtime.h>

// Problem constants (fixed by reference)
#define H    256
#define HE   64
#define NPB  512         // nodes per batch
#define MU_STEP (20.0f / 63.0f)
#define INV_SIG 3.2f     // 1/0.3125

// ---------------------------------------------------------------------------
__device__ __forceinline__ float wave_sum(float v) {
#pragma unroll
    for (int o = 32; o; o >>= 1) v += __shfl_xor(v, o, 64);
    return v;
}
__device__ __forceinline__ float wave_max(float v) {
#pragma unroll
    for (int o = 32; o; o >>= 1) v = fmaxf(v, __shfl_xor(v, o, 64));
    return v;
}
__device__ __forceinline__ float dot4(float4 a, float4 b, float acc) {
    return fmaf(a.x, b.x, fmaf(a.y, b.y, fmaf(a.z, b.z, fmaf(a.w, b.w, acc))));
}
__device__ __forceinline__ float4 add4(float4 a, float4 b) {
    return make_float4(a.x + b.x, a.y + b.y, a.z + b.z, a.w + b.w);
}

// ---------------------------------------------------------------------------
// Single kernel: everything, 2 anchors per block, raw weights.
// 256 blocks x 1024 threads (16 waves/CU, 1 block/CU).
// r26 (r25 measured 54.4us best, VALUBusy 37.5%, VGPR stuck at 64 ->
// compiler does NOT hold deeper flights; in-phase latency still exposed):
//  * manual double-buffered weight flights in B1/B2/upd/L1/L2/L3 (load
//    pass k+1 while computing pass k; static even/odd buffers)
//  * dense snf/rj, static trip counts (same lane->col coalesced pattern as
//    the measured r21/r25 gather — NOT r22's strided variant), deletes the
//    256-way-serialized LDS atomicAdd + idx indirection; snf depth-8
//    double-buffered, no tail
//  * idx_s/cnt_s removed (-4KB LDS)
// Watch: VGPR should rise to ~96-120 with no scratch (spill -> WRITE_SIZE).
// ---------------------------------------------------------------------------
__global__ void __launch_bounds__(1024, 4) fused_all(
    const float* __restrict__ anchor_x, const float* __restrict__ node_x,
    const float* __restrict__ anchor_f, const float* __restrict__ node_f,
    const float* __restrict__ node_mask,
    const float* __restrict__ Wq,  const float* __restrict__ bq,
    const float* __restrict__ Wkv, const float* __restrict__ bkv,
    const float* __restrict__ ln1_g, const float* __restrict__ ln1_b,
    const float* __restrict__ W1, const float* __restrict__ b1,
    const float* __restrict__ W2, const float* __restrict__ b2,
    const float* __restrict__ W3, const float* __restrict__ b3,
    const float* __restrict__ g2,  const float* __restrict__ bb2,
    float* __restrict__ out)
{
    const int bid = blockIdx.x;
    const int b  = bid & 7;                  // batch -> XCD
    const int pr = bid >> 3;                 // anchor pair 0..31
    const int aA = b * 64 + 2 * pr;
    const int aB = aA + 1;
    const int t  = threadIdx.x;              // 0..1023
    const int wv = t >> 6, l = t & 63;       // wave id (0..15), lane
    const int sub = l >> 4, kc16 = l & 15;   // wave-GEMV: output-sub, k-chunk

    __shared__ __align__(16) float qWp_s[2][2][324]; // [rowhalf][ha]: qW 0-255, qe 256-319
    __shared__ __align__(16) float q_s[2][256];
    __shared__ __align__(16) float af_s[2][256];   // anchor_f, later af1
    __shared__ __align__(16) float d10_s[2][NPB];
    __shared__ __align__(16) float mf_s[NPB];
    __shared__ __align__(16) float lg_s[2][NPB];
    __shared__ __align__(16) float w_s[2][NPB];
    __shared__ __align__(16) float snf_s[2][256], rj_s[2][64];
    __shared__ __align__(16) float m1_s[2][512], m2_s[2][512];
    __shared__ __align__(16) float red[512], red16[32];

    if (t < 128) {   // vectorized anchor_f stage (2 rows x 64 float4)
        int hh = t >> 6, tt = t & 63;
        ((float4*)af_s[hh])[tt] =
            ((const float4*)anchor_f)[(size_t)(hh ? aB : aA) * 64 + tt];
    }

    // Phase A: d10 for both anchors + mask factor, one node per thread (t<512)
    if (t < 512) {
        float axA0 = anchor_x[3 * aA], axA1 = anchor_x[3 * aA + 1], axA2 = anchor_x[3 * aA + 2];
        float axB0 = anchor_x[3 * aB], axB1 = anchor_x[3 * aB + 1], axB2 = anchor_x[3 * aB + 2];
        int ng = b * NPB + t;
        float nx0 = node_x[3 * ng], nx1 = node_x[3 * ng + 1], nx2 = node_x[3 * ng + 2];
        float dx = axA0 - nx0 + 1e-8f, dy = axA1 - nx1 + 1e-8f, dz = axA2 - nx2 + 1e-8f;
        d10_s[0][t] = sqrtf(dx * dx + dy * dy + dz * dz) * 0.1f;
        dx = axB0 - nx0 + 1e-8f; dy = axB1 - nx1 + 1e-8f; dz = axB2 - nx2 + 1e-8f;
        d10_s[1][t] = sqrtf(dx * dx + dy * dy + dz * dz) * 0.1f;
        mf_s[t] = (node_mask[ng] - 1.0f) * 1000000.0f;
    }
    __syncthreads();   // af_s, d10_s, mf_s ready

    // ---- Phase B1: q = bq + Wq.af (wave-GEMV, double-buffered flights) ----
    {
        float4 aA4[4], aB4[4];
#pragma unroll
        for (int v = 0; v < 4; ++v) {
            aA4[v] = ((const float4*)af_s[0])[16 * v + kc16];
            aB4[v] = ((const float4*)af_s[1])[16 * v + kc16];
        }
        float4 w0[4], w1[4];
        {
            const float4* wr = (const float4*)(Wq + (size_t)(wv * 4 + sub) * 256);
#pragma unroll
            for (int v = 0; v < 4; ++v) w0[v] = wr[16 * v + kc16];
        }
#pragma unroll
        for (int pass = 0; pass < 4; ++pass) {
            float4* wc = (pass & 1) ? w1 : w0;
            float4* wn = (pass & 1) ? w0 : w1;
            if (pass < 3) {
                const float4* wr = (const float4*)(Wq + (size_t)((pass + 1) * 64 + wv * 4 + sub) * 256);
#pragma unroll
                for (int v = 0; v < 4; ++v) wn[v] = wr[16 * v + kc16];
            }
            float aAc = 0.f, aBc = 0.f;
#pragma unroll
            for (int v = 0; v < 4; ++v) {
                aAc = dot4(wc[v], aA4[v], aAc);
                aBc = dot4(wc[v], aB4[v], aBc);
            }
#pragma unroll
            for (int o = 8; o >= 1; o >>= 1) {
                aAc += __shfl_xor(aAc, o, 64);
                aBc += __shfl_xor(aBc, o, 64);
            }
            if (kc16 == 0) {
                int m = pass * 64 + wv * 4 + sub;
                float bv = bq[m];
                q_s[0][m] = aAc + bv;
                q_s[1][m] = aBc + bv;
            }
        }
    }
    __syncthreads();   // q_s ready

    // ---- Phase B2: qW/qe column walk, deduped + row-split, dbuf 16-batches ----
    {
        int grp = -1, col = 0;
        if (t < 320)                   { grp = 0; col = t; }
        else if (t >= 512 && t < 832)  { grp = 1; col = t - 512; }
        if (grp >= 0) {
            const int r0 = grp * 128;
            const float* qsA = q_s[0] + r0;
            const float* qsB = q_s[1] + r0;
            float accA = 0.f, accB = 0.f;
            float wb0[16], wb1[16];
#pragma unroll
            for (int u = 0; u < 16; ++u) wb0[u] = Wkv[(size_t)(r0 + u) * 320 + col];
#pragma unroll
            for (int o = 0; o < 128; o += 32) {
#pragma unroll
                for (int u = 0; u < 16; ++u) wb1[u] = Wkv[(size_t)(r0 + o + 16 + u) * 320 + col];
#pragma unroll
                for (int u = 0; u < 16; ++u) {
                    accA = fmaf(wb0[u], qsA[o + u], accA);
                    accB = fmaf(wb0[u], qsB[o + u], accB);
                }
                if (o + 32 < 128) {
#pragma unroll
                    for (int u = 0; u < 16; ++u) wb0[u] = Wkv[(size_t)(r0 + o + 32 + u) * 320 + col];
                }
#pragma unroll
                for (int u = 0; u < 16; ++u) {
                    accA = fmaf(wb1[u], qsA[o + 16 + u], accA);
                    accB = fmaf(wb1[u], qsB[o + 16 + u], accB);
                }
            }
            qWp_s[grp][0][col] = accA;
            qWp_s[grp][1][col] = accB;
        }
    }
    // qbk: single wave-level reduce; the one barrier also publishes qWp_s.
    {
        float p = (t < 512) ? q_s[t >> 8][t & 255] * bkv[t & 255] : 0.f;
        p = wave_sum(p);
        if (l == 0) red16[wv] = p;
    }
    __syncthreads();   // qWp_s + red16 ready
    const float qbkA = red16[0] + red16[1] + red16[2] + red16[3];
    const float qbkB = red16[4] + red16[5] + red16[6] + red16[7];

    // ---- Phase C: logits, 16-lane groups, 4 nodes/wave/iter, depth-2 ----
    {
        const int g = sub;                    // node group 0..3
        float4 qA4[4], qB4[4];
#pragma unroll
        for (int v = 0; v < 4; ++v) {
            qA4[v] = add4(((const float4*)qWp_s[0][0])[4 * kc16 + v],
                          ((const float4*)qWp_s[1][0])[4 * kc16 + v]);
            qB4[v] = add4(((const float4*)qWp_s[0][1])[4 * kc16 + v],
                          ((const float4*)qWp_s[1][1])[4 * kc16 + v]);
        }
        const float4 qeA4 = add4(((const float4*)(qWp_s[0][0] + 256))[kc16],
                                 ((const float4*)(qWp_s[1][0] + 256))[kc16]);
        const float4 qeB4 = add4(((const float4*)(qWp_s[0][1] + 256))[kc16],
                                 ((const float4*)(qWp_s[1][1] + 256))[kc16]);
        const float mu0 = (4 * kc16 + 0) * MU_STEP, mu1 = (4 * kc16 + 1) * MU_STEP;
        const float mu2 = (4 * kc16 + 2) * MU_STEP, mu3 = (4 * kc16 + 3) * MU_STEP;
        const float4* nfb = (const float4*)(node_f + (size_t)(b * NPB) * 256);

        float4 f[4], fn[4];
        {
            const size_t r0 = (size_t)(wv * 4 + g) * 64 + 4 * kc16;
#pragma unroll
            for (int v = 0; v < 4; ++v) f[v] = nfb[r0 + v];
        }
        for (int it = 0; it < 8; ++it) {
            const int n = it * 64 + wv * 4 + g;
            if (it < 7) {
                const size_t r1 = (size_t)(n + 64) * 64 + 4 * kc16;
#pragma unroll
                for (int v = 0; v < 4; ++v) fn[v] = nfb[r1 + v];
            }
            float sA = 0.f, sB = 0.f;
#pragma unroll
            for (int v = 0; v < 4; ++v) {
                sA = dot4(f[v], qA4[v], sA);
                sB = dot4(f[v], qB4[v], sB);
            }
            const float dA10 = d10_s[0][n], dB10 = d10_s[1][n];
            float u;
            u = (dA10 - mu0) * INV_SIG; sA = fmaf(qeA4.x, __expf(-u * u), sA);
            u = (dA10 - mu1) * INV_SIG; sA = fmaf(qeA4.y, __expf(-u * u), sA);
            u = (dA10 - mu2) * INV_SIG; sA = fmaf(qeA4.z, __expf(-u * u), sA);
            u = (dA10 - mu3) * INV_SIG; sA = fmaf(qeA4.w, __expf(-u * u), sA);
            u = (dB10 - mu0) * INV_SIG; sB = fmaf(qeB4.x, __expf(-u * u), sB);
            u = (dB10 - mu1) * INV_SIG; sB = fmaf(qeB4.y, __expf(-u * u), sB);
            u = (dB10 - mu2) * INV_SIG; sB = fmaf(qeB4.z, __expf(-u * u), sB);
            u = (dB10 - mu3) * INV_SIG; sB = fmaf(qeB4.w, __expf(-u * u), sB);
#pragma unroll
            for (int o = 8; o >= 1; o >>= 1) {
                sA += __shfl_xor(sA, o, 64);
                sB += __shfl_xor(sB, o, 64);
            }
            if (kc16 == 0) {
                lg_s[0][n] = (sA + qbkA) * mf_s[n];
                lg_s[1][n] = (sB + qbkB) * mf_s[n];
            }
#pragma unroll
            for (int v = 0; v < 4; ++v) f[v] = fn[v];
        }
    }
    __syncthreads();

    // ---- Phase D: softmax, 2 barriers (disjoint red16 banks), no compaction ----
    const int h8 = t >> 9, n9 = t & 511;
    float lg = lg_s[h8][n9];
    {
        float m = wave_max(lg);
        if (l == 0) red16[wv] = m;
    }
    __syncthreads();
    float gmA = red16[0], gmB = red16[8];
#pragma unroll
    for (int i = 1; i < 8; ++i) { gmA = fmaxf(gmA, red16[i]); gmB = fmaxf(gmB, red16[8 + i]); }
    float e = __expf(lg - (h8 ? gmB : gmA));
    w_s[h8][n9] = e;
    {
        float sm = wave_sum(e);
        if (l == 0) red16[16 + wv] = sm;
    }
    __syncthreads();   // publishes w_s + sums
    float smA = 0.f, smB = 0.f;
#pragma unroll
    for (int i = 0; i < 8; ++i) { smA += red16[16 + i]; smB += red16[24 + i]; }
    const float invA = 1.0f / smA, invB = 1.0f / smB;

    // ---- snf dense (t<512, depth-8 dbuf, static 512) || rj dense (t>=512) ----
    if (t < 512) {
        const int hh = t >> 8, col = t & 255;
        const float* base = node_f + (size_t)(b * NPB) * 256 + col;
        const float* ws   = w_s[hh];
        float s = 0.f;
        float f0[8], f1[8];
#pragma unroll
        for (int u = 0; u < 8; ++u) f0[u] = base[(size_t)u * 256];
        for (int i = 0; i < 512; i += 16) {
#pragma unroll
            for (int u = 0; u < 8; ++u) f1[u] = base[(size_t)(i + 8 + u) * 256];
#pragma unroll
            for (int u = 0; u < 8; ++u) s = fmaf(ws[i + u], f0[u], s);
            if (i + 16 < 512) {
#pragma unroll
                for (int u = 0; u < 8; ++u) f0[u] = base[(size_t)(i + 16 + u) * 256];
            }
#pragma unroll
            for (int u = 0; u < 8; ++u) s = fmaf(ws[i + 8 + u], f1[u], s);
        }
        snf_s[hh][col] = s;
    } else {
        const int tt = t - 512;
        const int ha = tt >> 8, j = tt & 63, g4 = (tt >> 6) & 3;
        const float* ws = w_s[ha];
        const float* ds = d10_s[ha];
        const float mu = j * MU_STEP;
        float r0 = 0.f, r1 = 0.f, r2 = 0.f, r3 = 0.f;
        for (int i = g4; i < 512; i += 16) {
            float u0 = (ds[i]      - mu) * INV_SIG;
            float u1 = (ds[i + 4]  - mu) * INV_SIG;
            float u2 = (ds[i + 8]  - mu) * INV_SIG;
            float u3 = (ds[i + 12] - mu) * INV_SIG;
            r0 = fmaf(ws[i],      __expf(-u0 * u0), r0);
            r1 = fmaf(ws[i + 4],  __expf(-u1 * u1), r1);
            r2 = fmaf(ws[i + 8],  __expf(-u2 * u2), r2);
            r3 = fmaf(ws[i + 12], __expf(-u3 * u3), r3);
        }
        red[tt] = (r0 + r1) + (r2 + r3);
    }
    __syncthreads();
    if (t < 128) {
        int ha = t >> 6, j = t & 63;
        rj_s[ha][j] = red[ha * 256 + j] + red[ha * 256 + 64 + j]
                    + red[ha * 256 + 128 + j] + red[ha * 256 + 192 + j];
    }
    __syncthreads();

    // ---- upd wave-GEMV over raw Wkv v-rows (dbuf flights: 4+1) ----
    {
        float4 sA4[4], sB4[4];
#pragma unroll
        for (int v = 0; v < 4; ++v) {
            sA4[v] = ((const float4*)snf_s[0])[16 * v + kc16];
            sB4[v] = ((const float4*)snf_s[1])[16 * v + kc16];
        }
        const float4 rA4 = ((const float4*)rj_s[0])[kc16];
        const float4 rB4 = ((const float4*)rj_s[1])[kc16];
        float4 w0[4], w1[4], w40, w41;
        {
            const float4* wr = (const float4*)(Wkv + (size_t)(256 + wv * 4 + sub) * 320);
#pragma unroll
            for (int v = 0; v < 4; ++v) w0[v] = wr[16 * v + kc16];
            w40 = wr[64 + kc16];
        }
#pragma unroll
        for (int pass = 0; pass < 4; ++pass) {
            float4* wc = (pass & 1) ? w1 : w0;
            float4* wn = (pass & 1) ? w0 : w1;
            float4  w4c = (pass & 1) ? w41 : w40;
            if (pass < 3) {
                const float4* wr = (const float4*)(Wkv + (size_t)(256 + (pass + 1) * 64 + wv * 4 + sub) * 320);
#pragma unroll
                for (int v = 0; v < 4; ++v) wn[v] = wr[16 * v + kc16];
                if (pass & 1) w40 = wr[64 + kc16]; else w41 = wr[64 + kc16];
            }
            float aAc = 0.f, aBc = 0.f;
#pragma unroll
            for (int v = 0; v < 4; ++v) {
                aAc = dot4(wc[v], sA4[v], aAc);
                aBc = dot4(wc[v], sB4[v], aBc);
            }
            aAc = dot4(w4c, rA4, aAc);
            aBc = dot4(w4c, rB4, aBc);
#pragma unroll
            for (int o = 8; o >= 1; o >>= 1) {
                aAc += __shfl_xor(aAc, o, 64);
                aBc += __shfl_xor(aBc, o, 64);
            }
            if (kc16 == 0) {
                int m = pass * 64 + wv * 4 + sub;
                red[m] = aAc; red[256 + m] = aBc;
            }
        }
    }
    __syncthreads();

    // ---- residual + LN1, one-pass (sum + sumsq) ----
    const int h = (t >> 8) & 1, th = t & 255;
    float x = 0.f;
    if (t < 512)
        x = af_s[h][th] + red[h * 256 + th] * (h ? invB : invA) + bkv[256 + th];
    {
        float s1 = wave_sum(x);
        float s2 = wave_sum(x * x);
        if (l == 0) { red16[wv] = s1; red16[16 + wv] = s2; }
    }
    __syncthreads();
    {
        float meanA = (red16[0] + red16[1] + red16[2] + red16[3]) * (1.0f / 256.0f);
        float meanB = (red16[4] + red16[5] + red16[6] + red16[7]) * (1.0f / 256.0f);
        float sqA   = (red16[16] + red16[17] + red16[18] + red16[19]) * (1.0f / 256.0f);
        float sqB   = (red16[20] + red16[21] + red16[22] + red16[23]) * (1.0f / 256.0f);
        float varA = sqA - meanA * meanA, varB = sqB - meanB * meanB;
        if (t < 512) {
            float xc = x - (h ? meanB : meanA);
            af_s[h][th] = xc * rsqrtf((h ? varB : varA) + 1e-5f) * ln1_g[th] + ln1_b[th];
        }
    }
    __syncthreads();

    // ---- MLP L1 (8 passes, dbuf flights): m1 = relu(W1.af1 + b1) ----
    {
        float4 aA4[4], aB4[4];
#pragma unroll
        for (int v = 0; v < 4; ++v) {
            aA4[v] = ((const float4*)af_s[0])[16 * v + kc16];
            aB4[v] = ((const float4*)af_s[1])[16 * v + kc16];
        }
        float4 w0[4], w1[4];
        {
            const float4* wr = (const float4*)(W1 + (size_t)(wv * 4 + sub) * 256);
#pragma unroll
            for (int v = 0; v < 4; ++v) w0[v] = wr[16 * v + kc16];
        }
#pragma unroll
        for (int pass = 0; pass < 8; ++pass) {
            float4* wc = (pass & 1) ? w1 : w0;
            float4* wn = (pass & 1) ? w0 : w1;
            if (pass < 7) {
                const float4* wr = (const float4*)(W1 + (size_t)((pass + 1) * 64 + wv * 4 + sub) * 256);
#pragma unroll
                for (int v = 0; v < 4; ++v) wn[v] = wr[16 * v + kc16];
            }
            float aAc = 0.f, aBc = 0.f;
#pragma unroll
            for (int v = 0; v < 4; ++v) {
                aAc = dot4(wc[v], aA4[v], aAc);
                aBc = dot4(wc[v], aB4[v], aBc);
            }
#pragma unroll
            for (int o = 8; o >= 1; o >>= 1) {
                aAc += __shfl_xor(aAc, o, 64);
                aBc += __shfl_xor(aBc, o, 64);
            }
            if (kc16 == 0) {
                int m = pass * 64 + wv * 4 + sub;
                float bv = b1[m];
                m1_s[0][m] = fmaxf(aAc + bv, 0.f);
                m1_s[1][m] = fmaxf(aBc + bv, 0.f);
            }
        }
    }
    __syncthreads();

    // ---- MLP L2 (8 passes, half-flight dbuf): m2 = relu(W2.m1 + b2) ----
    {
        const float4* mA = (const float4*)m1_s[0];
        const float4* mB = (const float4*)m1_s[1];
        float4 w0[4], w1[4];
        {
            const float4* wr = (const float4*)(W2 + (size_t)(wv * 4 + sub) * 512);
#pragma unroll
            for (int v = 0; v < 4; ++v) w0[v] = wr[v * 16 + kc16];
        }
#pragma unroll
        for (int pass = 0; pass < 8; ++pass) {
            int m = pass * 64 + wv * 4 + sub;
            const float4* wr = (const float4*)(W2 + (size_t)m * 512);
            float aAc = 0.f, aBc = 0.f;
            // load half1 of this pass into w1, compute half0 from w0
#pragma unroll
            for (int v = 0; v < 4; ++v) w1[v] = wr[(4 + v) * 16 + kc16];
#pragma unroll
            for (int v = 0; v < 4; ++v) {
                aAc = dot4(w0[v], mA[v * 16 + kc16], aAc);
                aBc = dot4(w0[v], mB[v * 16 + kc16], aBc);
            }
            // load half0 of next pass into w0, compute half1 from w1
            if (pass < 7) {
                const float4* wrn = (const float4*)(W2 + (size_t)(m + 64) * 512);
#pragma unroll
                for (int v = 0; v < 4; ++v) w0[v] = wrn[v * 16 + kc16];
            }
#pragma unroll
            for (int v = 0; v < 4; ++v) {
                aAc = dot4(w1[v], mA[(4 + v) * 16 + kc16], aAc);
                aBc = dot4(w1[v], mB[(4 + v) * 16 + kc16], aBc);
            }
#pragma unroll
            for (int o = 8; o >= 1; o >>= 1) {
                aAc += __shfl_xor(aAc, o, 64);
                aBc += __shfl_xor(aBc, o, 64);
            }
            if (kc16 == 0) {
                float bv = b2[m];
                m2_s[0][m] = fmaxf(aAc + bv, 0.f);
                m2_s[1][m] = fmaxf(aBc + bv, 0.f);
            }
        }
    }
    __syncthreads();

    // ---- MLP L3 (4 passes, half-flight dbuf): y = W3.m2 + b3 -> red[] ----
    {
        const float4* mA = (const float4*)m2_s[0];
        const float4* mB = (const float4*)m2_s[1];
        float4 w0[4], w1[4];
        {
            const float4* wr = (const float4*)(W3 + (size_t)(wv * 4 + sub) * 512);
#pragma unroll
            for (int v = 0; v < 4; ++v) w0[v] = wr[v * 16 + kc16];
        }
#pragma unroll
        for (int pass = 0; pass < 4; ++pass) {
            int m = pass * 64 + wv * 4 + sub;
            const float4* wr = (const float4*)(W3 + (size_t)m * 512);
            float aAc = 0.f, aBc = 0.f;
#pragma unroll
            for (int v = 0; v < 4; ++v) w1[v] = wr[(4 + v) * 16 + kc16];
#pragma unroll
            for (int v = 0; v < 4; ++v) {
                aAc = dot4(w0[v], mA[v * 16 + kc16], aAc);
                aBc = dot4(w0[v], mB[v * 16 + kc16], aBc);
            }
            if (pass < 3) {
                const float4* wrn = (const float4*)(W3 + (size_t)(m + 64) * 512);
#pragma unroll
                for (int v = 0; v < 4; ++v) w0[v] = wrn[v * 16 + kc16];
            }
#pragma unroll
            for (int v = 0; v < 4; ++v) {
                aAc = dot4(w1[v], mA[(4 + v) * 16 + kc16], aAc);
                aBc = dot4(w1[v], mB[(4 + v) * 16 + kc16], aBc);
            }
#pragma unroll
            for (int o = 8; o >= 1; o >>= 1) {
                aAc += __shfl_xor(aAc, o, 64);
                aBc += __shfl_xor(aBc, o, 64);
            }
            if (kc16 == 0) {
                float bv = b3[m];
                red[m]       = aAc + bv;
                red[256 + m] = aBc + bv;
            }
        }
    }
    __syncthreads();

    // ---- residual + LN2, one-pass -> out ----
    float y = 0.f;
    if (t < 512) y = red[h * 256 + th] + af_s[h][th];
    {
        float s1 = wave_sum(y);
        float s2 = wave_sum(y * y);
        if (l == 0) { red16[wv] = s1; red16[16 + wv] = s2; }
    }
    __syncthreads();
    {
        float mnA = (red16[0] + red16[1] + red16[2] + red16[3]) * (1.0f / 256.0f);
        float mnB = (red16[4] + red16[5] + red16[6] + red16[7]) * (1.0f / 256.0f);
        float sqA = (red16[16] + red16[17] + red16[18] + red16[19]) * (1.0f / 256.0f);
        float sqB = (red16[20] + red16[21] + red16[22] + red16[23]) * (1.0f / 256.0f);
        float vrA = sqA - mnA * mnA, vrB = sqB - mnB * mnB;
        if (t < 512) {
            float yc = y - (h ? mnB : mnA);
            int aOut = h ? aB : aA;
            out[(size_t)aOut * 256 + th] =
                yc * rsqrtf((h ? vrB : vrA) + 1e-5f) * g2[th] + bb2[th];
        }
    }
}

// ---------------------------------------------------------------------------
extern "C" void kernel_launch(void* const* d_in, const int* in_sizes, int n_in,
                              void* d_out, int out_size, void* d_ws, size_t ws_size,
                              hipStream_t stream)
{
    const float* anchor_x  = (const float*)d_in[0];
    const float* node_x    = (const float*)d_in[1];
    const float* anchor_f  = (const float*)d_in[2];
    const float* node_f    = (const float*)d_in[3];
    const float* node_mask = (const float*)d_in[6];
    const float* Wq        = (const float*)d_in[7];
    const float* bq        = (const float*)d_in[8];
    const float* Wkv       = (const float*)d_in[9];
    const float* bkv       = (const float*)d_in[10];
    const float* ln1_g     = (const float*)d_in[11];
    const float* ln1_b     = (const float*)d_in[12];
    const float* W1        = (const float*)d_in[13];
    const float* b1        = (const float*)d_in[14];
    const float* W2        = (const float*)d_in[15];
    const float* b2        = (const float*)d_in[16];
    const float* W3        = (const float*)d_in[17];
    const float* b3        = (const float*)d_in[18];
    const float* ln2_g     = (const float*)d_in[19];
    const float* ln2_b     = (const float*)d_in[20];

    fused_all<<<256, 1024, 0, stream>>>(anchor_x, node_x, anchor_f, node_f,
                                        node_mask, Wq, bq, Wkv, bkv,
                                        ln1_g, ln1_b, W1, b1, W2, b2, W3, b3,
                                        ln2_g, ln2_b, (float*)d_out);
}

// Round 8
// 140.022 us; speedup vs baseline: 1.0947x; 1.0947x over previous
//
#include <hip/hip_runtime.h>

// Problem constants (fixed by reference)
#define H    256
#define HE   64
#define NPB  512         // nodes per batch
#define MU_STEP (20.0f / 63.0f)
#define INV_SIG 3.2f     // 1/0.3125

// ---------------------------------------------------------------------------
__device__ __forceinline__ float wave_sum(float v) {
#pragma unroll
    for (int o = 32; o; o >>= 1) v += __shfl_xor(v, o, 64);
    return v;
}
__device__ __forceinline__ float wave_max(float v) {
#pragma unroll
    for (int o = 32; o; o >>= 1) v = fmaxf(v, __shfl_xor(v, o, 64));
    return v;
}
__device__ __forceinline__ float dot4(float4 a, float4 b, float acc) {
    return fmaf(a.x, b.x, fmaf(a.y, b.y, fmaf(a.z, b.z, fmaf(a.w, b.w, acc))));
}
__device__ __forceinline__ float4 add4(float4 a, float4 b) {
    return make_float4(a.x + b.x, a.y + b.y, a.z + b.z, a.w + b.w);
}

// ---------------------------------------------------------------------------
// Single kernel: everything, 2 anchors per block, raw weights.
// 256 blocks x 1024 threads (16 waves/CU, 1 block/CU).
// r27 = r25 (measured 54.4us best) + pass-paired B1/L1.
// History: r26's manual dbuf+dense-snf REGRESSED (65us, VALU busy +40%,
// VGPR stuck 64 -> swaps were pure instruction overhead) — reverted.
// r25's measured wins kept verbatim: B2 dedup+rowsplit, W2/W3 8-float4
// flights, launch_bounds(1024,4), compacted snf/rj gather.
// New (same axis as the W2/W3 win, no swaps): B1 4->2 superpasses and
// L1 8->4 superpasses, each loading TWO rows' weights (8 independent
// float4) before computing both — 8 outstanding loads vs 4 against L2
// latency. Instruction count unchanged.
// ---------------------------------------------------------------------------
__global__ void __launch_bounds__(1024, 4) fused_all(
    const float* __restrict__ anchor_x, const float* __restrict__ node_x,
    const float* __restrict__ anchor_f, const float* __restrict__ node_f,
    const float* __restrict__ node_mask,
    const float* __restrict__ Wq,  const float* __restrict__ bq,
    const float* __restrict__ Wkv, const float* __restrict__ bkv,
    const float* __restrict__ ln1_g, const float* __restrict__ ln1_b,
    const float* __restrict__ W1, const float* __restrict__ b1,
    const float* __restrict__ W2, const float* __restrict__ b2,
    const float* __restrict__ W3, const float* __restrict__ b3,
    const float* __restrict__ g2,  const float* __restrict__ bb2,
    float* __restrict__ out)
{
    const int bid = blockIdx.x;
    const int b  = bid & 7;                  // batch -> XCD
    const int pr = bid >> 3;                 // anchor pair 0..31
    const int aA = b * 64 + 2 * pr;
    const int aB = aA + 1;
    const int t  = threadIdx.x;              // 0..1023
    const int wv = t >> 6, l = t & 63;       // wave id (0..15), lane
    const int sub = l >> 4, kc16 = l & 15;   // wave-GEMV: output-sub, k-chunk

    __shared__ __align__(16) float qWp_s[2][2][324]; // [rowhalf][ha]: qW 0-255, qe 256-319
    __shared__ __align__(16) float q_s[2][256];
    __shared__ __align__(16) float af_s[2][256];   // anchor_f, later af1
    __shared__ __align__(16) float d10_s[2][NPB];
    __shared__ __align__(16) float mf_s[NPB];
    __shared__ __align__(16) float lg_s[2][NPB];
    __shared__ __align__(16) float w_s[2][NPB];
    __shared__ __align__(16) float snf_s[2][256], rj_s[2][64];
    __shared__ __align__(16) float m1_s[2][512], m2_s[2][512];
    __shared__ __align__(16) float red[512], red16[32];
    __shared__ int   idx_s[2][NPB];
    __shared__ int   cnt_s[2];

    if (t < 128) {   // vectorized anchor_f stage (2 rows x 64 float4)
        int hh = t >> 6, tt = t & 63;
        ((float4*)af_s[hh])[tt] =
            ((const float4*)anchor_f)[(size_t)(hh ? aB : aA) * 64 + tt];
    }
    if (t < 2) cnt_s[t] = 0;

    // Phase A: d10 for both anchors + mask factor, one node per thread (t<512)
    if (t < 512) {
        float axA0 = anchor_x[3 * aA], axA1 = anchor_x[3 * aA + 1], axA2 = anchor_x[3 * aA + 2];
        float axB0 = anchor_x[3 * aB], axB1 = anchor_x[3 * aB + 1], axB2 = anchor_x[3 * aB + 2];
        int ng = b * NPB + t;
        float nx0 = node_x[3 * ng], nx1 = node_x[3 * ng + 1], nx2 = node_x[3 * ng + 2];
        float dx = axA0 - nx0 + 1e-8f, dy = axA1 - nx1 + 1e-8f, dz = axA2 - nx2 + 1e-8f;
        d10_s[0][t] = sqrtf(dx * dx + dy * dy + dz * dz) * 0.1f;
        dx = axB0 - nx0 + 1e-8f; dy = axB1 - nx1 + 1e-8f; dz = axB2 - nx2 + 1e-8f;
        d10_s[1][t] = sqrtf(dx * dx + dy * dy + dz * dz) * 0.1f;
        mf_s[t] = (node_mask[ng] - 1.0f) * 1000000.0f;
    }
    __syncthreads();   // af_s, cnt_s, d10_s, mf_s ready

    // ---- Phase B1: q = bq + Wq.af  (2 superpasses, 8-float4 flights) ----
    {
        float4 aA4[4], aB4[4];
#pragma unroll
        for (int v = 0; v < 4; ++v) {
            aA4[v] = ((const float4*)af_s[0])[16 * v + kc16];
            aB4[v] = ((const float4*)af_s[1])[16 * v + kc16];
        }
#pragma unroll
        for (int sp = 0; sp < 2; ++sp) {
            const int m0 = sp * 128 + wv * 4 + sub;
            const int m1 = m0 + 64;
            const float4* wr0 = (const float4*)(Wq + (size_t)m0 * 256);
            const float4* wr1 = (const float4*)(Wq + (size_t)m1 * 256);
            float4 w[8];
#pragma unroll
            for (int v = 0; v < 4; ++v) { w[v] = wr0[16 * v + kc16]; w[4 + v] = wr1[16 * v + kc16]; }
            float a0A = 0.f, a0B = 0.f, a1A = 0.f, a1B = 0.f;
#pragma unroll
            for (int v = 0; v < 4; ++v) {
                a0A = dot4(w[v],     aA4[v], a0A);
                a0B = dot4(w[v],     aB4[v], a0B);
                a1A = dot4(w[4 + v], aA4[v], a1A);
                a1B = dot4(w[4 + v], aB4[v], a1B);
            }
#pragma unroll
            for (int o = 8; o >= 1; o >>= 1) {
                a0A += __shfl_xor(a0A, o, 64);
                a0B += __shfl_xor(a0B, o, 64);
                a1A += __shfl_xor(a1A, o, 64);
                a1B += __shfl_xor(a1B, o, 64);
            }
            if (kc16 == 0) {
                q_s[0][m0] = a0A + bq[m0];
                q_s[1][m0] = a0B + bq[m0];
                q_s[0][m1] = a1A + bq[m1];
                q_s[1][m1] = a1B + bq[m1];
            }
        }
    }
    __syncthreads();   // q_s ready

    // ---- Phase B2: qW/qe column walk, deduped (one read -> both anchors),
    //      row-split: grp0 = rows 0..127, grp1 = rows 128..255 ----
    {
        int grp = -1, col = 0;
        if (t < 320)                   { grp = 0; col = t; }
        else if (t >= 512 && t < 832)  { grp = 1; col = t - 512; }
        if (grp >= 0) {
            const int r0 = grp * 128;
            const float* qsA = q_s[0] + r0;
            const float* qsB = q_s[1] + r0;
            float accA = 0.f, accB = 0.f;
            for (int o = 0; o < 128; o += 16) {
                float w16[16];
#pragma unroll
                for (int u = 0; u < 16; ++u) w16[u] = Wkv[(size_t)(r0 + o + u) * 320 + col];
#pragma unroll
                for (int u = 0; u < 16; ++u) {
                    accA = fmaf(w16[u], qsA[o + u], accA);
                    accB = fmaf(w16[u], qsB[o + u], accB);
                }
            }
            qWp_s[grp][0][col] = accA;
            qWp_s[grp][1][col] = accB;
        }
    }
    // qbk: single wave-level reduce; the one barrier also publishes qWp_s.
    {
        float p = (t < 512) ? q_s[t >> 8][t & 255] * bkv[t & 255] : 0.f;
        p = wave_sum(p);
        if (l == 0) red16[wv] = p;
    }
    __syncthreads();   // qWp_s + red16 ready
    const float qbkA = red16[0] + red16[1] + red16[2] + red16[3];
    const float qbkB = red16[4] + red16[5] + red16[6] + red16[7];

    // ---- Phase C: logits, 16-lane groups, 4 nodes/wave/iter, depth-2 ----
    {
        const int g = sub;                    // node group 0..3
        float4 qA4[4], qB4[4];
#pragma unroll
        for (int v = 0; v < 4; ++v) {
            qA4[v] = add4(((const float4*)qWp_s[0][0])[4 * kc16 + v],
                          ((const float4*)qWp_s[1][0])[4 * kc16 + v]);
            qB4[v] = add4(((const float4*)qWp_s[0][1])[4 * kc16 + v],
                          ((const float4*)qWp_s[1][1])[4 * kc16 + v]);
        }
        const float4 qeA4 = add4(((const float4*)(qWp_s[0][0] + 256))[kc16],
                                 ((const float4*)(qWp_s[1][0] + 256))[kc16]);
        const float4 qeB4 = add4(((const float4*)(qWp_s[0][1] + 256))[kc16],
                                 ((const float4*)(qWp_s[1][1] + 256))[kc16]);
        const float mu0 = (4 * kc16 + 0) * MU_STEP, mu1 = (4 * kc16 + 1) * MU_STEP;
        const float mu2 = (4 * kc16 + 2) * MU_STEP, mu3 = (4 * kc16 + 3) * MU_STEP;
        const float4* nfb = (const float4*)(node_f + (size_t)(b * NPB) * 256);

        float4 f[4], fn[4];
        {
            const size_t r0 = (size_t)(wv * 4 + g) * 64 + 4 * kc16;
#pragma unroll
            for (int v = 0; v < 4; ++v) f[v] = nfb[r0 + v];
        }
        for (int it = 0; it < 8; ++it) {
            const int n = it * 64 + wv * 4 + g;
            if (it < 7) {
                const size_t r1 = (size_t)(n + 64) * 64 + 4 * kc16;
#pragma unroll
                for (int v = 0; v < 4; ++v) fn[v] = nfb[r1 + v];
            }
            float sA = 0.f, sB = 0.f;
#pragma unroll
            for (int v = 0; v < 4; ++v) {
                sA = dot4(f[v], qA4[v], sA);
                sB = dot4(f[v], qB4[v], sB);
            }
            const float dA10 = d10_s[0][n], dB10 = d10_s[1][n];
            float u;
            u = (dA10 - mu0) * INV_SIG; sA = fmaf(qeA4.x, __expf(-u * u), sA);
            u = (dA10 - mu1) * INV_SIG; sA = fmaf(qeA4.y, __expf(-u * u), sA);
            u = (dA10 - mu2) * INV_SIG; sA = fmaf(qeA4.z, __expf(-u * u), sA);
            u = (dA10 - mu3) * INV_SIG; sA = fmaf(qeA4.w, __expf(-u * u), sA);
            u = (dB10 - mu0) * INV_SIG; sB = fmaf(qeB4.x, __expf(-u * u), sB);
            u = (dB10 - mu1) * INV_SIG; sB = fmaf(qeB4.y, __expf(-u * u), sB);
            u = (dB10 - mu2) * INV_SIG; sB = fmaf(qeB4.z, __expf(-u * u), sB);
            u = (dB10 - mu3) * INV_SIG; sB = fmaf(qeB4.w, __expf(-u * u), sB);
#pragma unroll
            for (int o = 8; o >= 1; o >>= 1) {
                sA += __shfl_xor(sA, o, 64);
                sB += __shfl_xor(sB, o, 64);
            }
            if (kc16 == 0) {
                lg_s[0][n] = (sA + qbkA) * mf_s[n];
                lg_s[1][n] = (sB + qbkB) * mf_s[n];
            }
#pragma unroll
            for (int v = 0; v < 4; ++v) f[v] = fn[v];
        }
    }
    __syncthreads();

    // ---- Phase D: softmax, 2 barriers (disjoint red16 banks) ----
    const int h8 = t >> 9, n9 = t & 511;
    float lg = lg_s[h8][n9];
    {
        float m = wave_max(lg);
        if (l == 0) red16[wv] = m;
    }
    __syncthreads();
    float gmA = red16[0], gmB = red16[8];
#pragma unroll
    for (int i = 1; i < 8; ++i) { gmA = fmaxf(gmA, red16[i]); gmB = fmaxf(gmB, red16[8 + i]); }
    float e = __expf(lg - (h8 ? gmB : gmA));
    w_s[h8][n9] = e;
    {
        float sm = wave_sum(e);
        if (l == 0) red16[16 + wv] = sm;
    }
    if (e > 0.f) { int p = atomicAdd(&cnt_s[h8], 1); idx_s[h8][p] = n9; }
    __syncthreads();   // publishes w_s, sums, idx, cnt in one barrier
    float smA = 0.f, smB = 0.f;
#pragma unroll
    for (int i = 0; i < 8; ++i) { smA += red16[16 + i]; smB += red16[24 + i]; }
    const float invA = 1.0f / smA, invB = 1.0f / smB;

    // ---- snf (t<512, 16-deep pipelined) || rj partials (t>=512, 4-deep) ----
    if (t < 512) {
        const int hh = t >> 8, col = t & 255;
        const int cnt = cnt_s[hh];
        const float* base = node_f + (size_t)(b * NPB) * 256 + col;
        const int*   idx  = idx_s[hh];
        const float* ws   = w_s[hh];
        float s = 0.f;
        int i = 0;
        for (; i + 16 <= cnt; i += 16) {
            int   n[16];
            float f[16];
#pragma unroll
            for (int u = 0; u < 16; ++u) n[u] = idx[i + u];
#pragma unroll
            for (int u = 0; u < 16; ++u) f[u] = base[(size_t)n[u] * 256];
#pragma unroll
            for (int u = 0; u < 16; ++u) s = fmaf(ws[n[u]], f[u], s);
        }
        for (; i < cnt; ++i) { int n = idx[i]; s = fmaf(ws[n], base[(size_t)n * 256], s); }
        snf_s[hh][col] = s;
    } else {
        const int tt = t - 512;
        const int ha = tt >> 8, j = tt & 63, g = (tt >> 6) & 3;
        const int cnt = cnt_s[ha];
        const int*   idx = idx_s[ha];
        const float* ws  = w_s[ha];
        const float* ds  = d10_s[ha];
        const float mu = j * MU_STEP;
        float r = 0.f;
        int i = g;
        for (; i + 12 < cnt; i += 16) {
            int n0 = idx[i], n1 = idx[i + 4], n2 = idx[i + 8], n3 = idx[i + 12];
            float u0 = (ds[n0] - mu) * INV_SIG, u1 = (ds[n1] - mu) * INV_SIG;
            float u2 = (ds[n2] - mu) * INV_SIG, u3 = (ds[n3] - mu) * INV_SIG;
            r = fmaf(ws[n0], __expf(-u0 * u0), r);
            r = fmaf(ws[n1], __expf(-u1 * u1), r);
            r = fmaf(ws[n2], __expf(-u2 * u2), r);
            r = fmaf(ws[n3], __expf(-u3 * u3), r);
        }
        for (; i < cnt; i += 4) {
            int n = idx[i];
            float uu = (ds[n] - mu) * INV_SIG;
            r = fmaf(ws[n], __expf(-uu * uu), r);
        }
        red[tt] = r;
    }
    __syncthreads();
    if (t < 128) {
        int ha = t >> 6, j = t & 63;
        rj_s[ha][j] = red[ha * 256 + j] + red[ha * 256 + 64 + j]
                    + red[ha * 256 + 128 + j] + red[ha * 256 + 192 + j];
    }
    __syncthreads();

    // ---- upd wave-GEMV over raw Wkv v-rows (float4 flights: 4+1) ----
    {
        float4 sA4[4], sB4[4];
#pragma unroll
        for (int v = 0; v < 4; ++v) {
            sA4[v] = ((const float4*)snf_s[0])[16 * v + kc16];
            sB4[v] = ((const float4*)snf_s[1])[16 * v + kc16];
        }
        const float4 rA4 = ((const float4*)rj_s[0])[kc16];
        const float4 rB4 = ((const float4*)rj_s[1])[kc16];
#pragma unroll
        for (int pass = 0; pass < 4; ++pass) {
            int m = pass * 64 + wv * 4 + sub;
            const float4* wr = (const float4*)(Wkv + (size_t)(256 + m) * 320);
            float4 w[4];
#pragma unroll
            for (int v = 0; v < 4; ++v) w[v] = wr[16 * v + kc16];
            float4 w4 = wr[64 + kc16];
            float aAc = 0.f, aBc = 0.f;
#pragma unroll
            for (int v = 0; v < 4; ++v) {
                aAc = dot4(w[v], sA4[v], aAc);
                aBc = dot4(w[v], sB4[v], aBc);
            }
            aAc = dot4(w4, rA4, aAc);
            aBc = dot4(w4, rB4, aBc);
#pragma unroll
            for (int o = 8; o >= 1; o >>= 1) {
                aAc += __shfl_xor(aAc, o, 64);
                aBc += __shfl_xor(aBc, o, 64);
            }
            if (kc16 == 0) { red[m] = aAc; red[256 + m] = aBc; }
        }
    }
    __syncthreads();

    // ---- residual + LN1, one-pass (sum + sumsq) ----
    const int h = (t >> 8) & 1, th = t & 255;
    float x = 0.f;
    if (t < 512)
        x = af_s[h][th] + red[h * 256 + th] * (h ? invB : invA) + bkv[256 + th];
    {
        float s1 = wave_sum(x);
        float s2 = wave_sum(x * x);
        if (l == 0) { red16[wv] = s1; red16[16 + wv] = s2; }
    }
    __syncthreads();
    {
        float meanA = (red16[0] + red16[1] + red16[2] + red16[3]) * (1.0f / 256.0f);
        float meanB = (red16[4] + red16[5] + red16[6] + red16[7]) * (1.0f / 256.0f);
        float sqA   = (red16[16] + red16[17] + red16[18] + red16[19]) * (1.0f / 256.0f);
        float sqB   = (red16[20] + red16[21] + red16[22] + red16[23]) * (1.0f / 256.0f);
        float varA = sqA - meanA * meanA, varB = sqB - meanB * meanB;
        if (t < 512) {
            float xc = x - (h ? meanB : meanA);
            af_s[h][th] = xc * rsqrtf((h ? varB : varA) + 1e-5f) * ln1_g[th] + ln1_b[th];
        }
    }
    __syncthreads();

    // ---- MLP L1 (4 superpasses, 8-float4 flights): m1 = relu(W1.af1 + b1) ----
    {
        float4 aA4[4], aB4[4];
#pragma unroll
        for (int v = 0; v < 4; ++v) {
            aA4[v] = ((const float4*)af_s[0])[16 * v + kc16];
            aB4[v] = ((const float4*)af_s[1])[16 * v + kc16];
        }
#pragma unroll
        for (int sp = 0; sp < 4; ++sp) {
            const int m0 = sp * 128 + wv * 4 + sub;
            const int m1 = m0 + 64;
            const float4* wr0 = (const float4*)(W1 + (size_t)m0 * 256);
            const float4* wr1 = (const float4*)(W1 + (size_t)m1 * 256);
            float4 w[8];
#pragma unroll
            for (int v = 0; v < 4; ++v) { w[v] = wr0[16 * v + kc16]; w[4 + v] = wr1[16 * v + kc16]; }
            float a0A = 0.f, a0B = 0.f, a1A = 0.f, a1B = 0.f;
#pragma unroll
            for (int v = 0; v < 4; ++v) {
                a0A = dot4(w[v],     aA4[v], a0A);
                a0B = dot4(w[v],     aB4[v], a0B);
                a1A = dot4(w[4 + v], aA4[v], a1A);
                a1B = dot4(w[4 + v], aB4[v], a1B);
            }
#pragma unroll
            for (int o = 8; o >= 1; o >>= 1) {
                a0A += __shfl_xor(a0A, o, 64);
                a0B += __shfl_xor(a0B, o, 64);
                a1A += __shfl_xor(a1A, o, 64);
                a1B += __shfl_xor(a1B, o, 64);
            }
            if (kc16 == 0) {
                m1_s[0][m0] = fmaxf(a0A + b1[m0], 0.f);
                m1_s[1][m0] = fmaxf(a0B + b1[m0], 0.f);
                m1_s[0][m1] = fmaxf(a1A + b1[m1], 0.f);
                m1_s[1][m1] = fmaxf(a1B + b1[m1], 0.f);
            }
        }
    }
    __syncthreads();

    // ---- MLP L2 (8 passes, 8-float4 flight): m2 = relu(W2.m1 + b2) ----
#pragma unroll
    for (int pass = 0; pass < 8; ++pass) {
        int m = pass * 64 + wv * 4 + sub;
        const float4* wr = (const float4*)(W2 + (size_t)m * 512);
        float4 w[8];
#pragma unroll
        for (int k = 0; k < 8; ++k) w[k] = wr[k * 16 + kc16];
        const float4* mA = (const float4*)m1_s[0];
        const float4* mB = (const float4*)m1_s[1];
        float aAc = 0.f, aBc = 0.f;
#pragma unroll
        for (int k = 0; k < 8; ++k) {
            aAc = dot4(w[k], mA[k * 16 + kc16], aAc);
            aBc = dot4(w[k], mB[k * 16 + kc16], aBc);
        }
#pragma unroll
        for (int o = 8; o >= 1; o >>= 1) {
            aAc += __shfl_xor(aAc, o, 64);
            aBc += __shfl_xor(aBc, o, 64);
        }
        if (kc16 == 0) {
            float bv = b2[m];
            m2_s[0][m] = fmaxf(aAc + bv, 0.f);
            m2_s[1][m] = fmaxf(aBc + bv, 0.f);
        }
    }
    __syncthreads();

    // ---- MLP L3 (4 passes, 8-float4 flight): y = W3.m2 + b3 -> red[] ----
#pragma unroll
    for (int pass = 0; pass < 4; ++pass) {
        int m = pass * 64 + wv * 4 + sub;
        const float4* wr = (const float4*)(W3 + (size_t)m * 512);
        float4 w[8];
#pragma unroll
        for (int k = 0; k < 8; ++k) w[k] = wr[k * 16 + kc16];
        const float4* mA = (const float4*)m2_s[0];
        const float4* mB = (const float4*)m2_s[1];
        float aAc = 0.f, aBc = 0.f;
#pragma unroll
        for (int k = 0; k < 8; ++k) {
            aAc = dot4(w[k], mA[k * 16 + kc16], aAc);
            aBc = dot4(w[k], mB[k * 16 + kc16], aBc);
        }
#pragma unroll
        for (int o = 8; o >= 1; o >>= 1) {
            aAc += __shfl_xor(aAc, o, 64);
            aBc += __shfl_xor(aBc, o, 64);
        }
        if (kc16 == 0) {
            float bv = b3[m];
            red[m]       = aAc + bv;
            red[256 + m] = aBc + bv;
        }
    }
    __syncthreads();

    // ---- residual + LN2, one-pass -> out ----
    float y = 0.f;
    if (t < 512) y = red[h * 256 + th] + af_s[h][th];
    {
        float s1 = wave_sum(y);
        float s2 = wave_sum(y * y);
        if (l == 0) { red16[wv] = s1; red16[16 + wv] = s2; }
    }
    __syncthreads();
    {
        float mnA = (red16[0] + red16[1] + red16[2] + red16[3]) * (1.0f / 256.0f);
        float mnB = (red16[4] + red16[5] + red16[6] + red16[7]) * (1.0f / 256.0f);
        float sqA = (red16[16] + red16[17] + red16[18] + red16[19]) * (1.0f / 256.0f);
        float sqB = (red16[20] + red16[21] + red16[22] + red16[23]) * (1.0f / 256.0f);
        float vrA = sqA - mnA * mnA, vrB = sqB - mnB * mnB;
        if (t < 512) {
            float yc = y - (h ? mnB : mnA);
            int aOut = h ? aB : aA;
            out[(size_t)aOut * 256 + th] =
                yc * rsqrtf((h ? vrB : vrA) + 1e-5f) * g2[th] + bb2[th];
        }
    }
}

// ---------------------------------------------------------------------------
extern "C" void kernel_launch(void* const* d_in, const int* in_sizes, int n_in,
                              void* d_out, int out_size, void* d_ws, size_t ws_size,
                              hipStream_t stream)
{
    const float* anchor_x  = (const float*)d_in[0];
    const float* node_x    = (const float*)d_in[1];
    const float* anchor_f  = (const float*)d_in[2];
    const float* node_f    = (const float*)d_in[3];
    const float* node_mask = (const float*)d_in[6];
    const float* Wq        = (const float*)d_in[7];
    const float* bq        = (const float*)d_in[8];
    const float* Wkv       = (const float*)d_in[9];
    const float* bkv       = (const float*)d_in[10];
    const float* ln1_g     = (const float*)d_in[11];
    const float* ln1_b     = (const float*)d_in[12];
    const float* W1        = (const float*)d_in[13];
    const float* b1        = (const float*)d_in[14];
    const float* W2        = (const float*)d_in[15];
    const float* b2        = (const float*)d_in[16];
    const float* W3        = (const float*)d_in[17];
    const float* b3        = (const float*)d_in[18];
    const float* ln2_g     = (const float*)d_in[19];
    const float* ln2_b     = (const float*)d_in[20];

    fused_all<<<256, 1024, 0, stream>>>(anchor_x, node_x, anchor_f, node_f,
                                        node_mask, Wq, bq, Wkv, bkv,
                                        ln1_g, ln1_b, W1, b1, W2, b2, W3, b3,
                                        ln2_g, ln2_b, (float*)d_out);
}